// Round 2
// baseline (437.539 us; speedup 1.0000x reference)
//
#include <hip/hip_runtime.h>

// SubsetSampler: out0 = x (f32 passthrough), out1 = float(mask | (l >= cutoff)),
// cutoff_b = min(ceil(0.7 * count_false(mask[b,:])), L-1).  B=8192, L=4096.
//
// R6: wave-per-row (no LDS/barriers, like R5) but register-lean for occupancy.
// R5 post-mortem: xv[16] (64 VGPR) + mw[16] pushed VGPR >100 -> 4 waves/SIMD
// (occupancy steps at 64/128 VGPR), halving TLP vs the R4 block-per-row
// version; remainder went 86 -> 94 us. Fix: stage x depth-2 x 4 chunks
// (xa/xb = 32 VGPR), peak live ~58 regs, __launch_bounds__(256,8) pins <=64
// -> 8 waves/SIMD. 8 outstanding 16B loads/wave x 8 waves = 1 KB/SIMD in
// flight, enough for the ~2.4 TB/s read side (writes need no latency hiding).
// Harness-fixed: ~330 us poison fills. Controllable floor ~= 436 MB @ 6.5 TB/s
// = 67 us + detect ~4 us.

#define L_DIM 4096
#define SUBSET_RATE 0.7f

typedef float        f32x4 __attribute__((ext_vector_type(4)));
typedef unsigned int u32x4 __attribute__((ext_vector_type(4)));

// ---- mask-storage detection (1 block, 16 KB read, ~4 us) --------------------
// byte bools: padding runs of 0x01 -> some word > 1 in the first 4096 words.
// f32 bools: word 0x3f800000. int32 bools: words 0/1 only. Word-sized layouts
// (int32/f32) share the decode path (nonzero == True). mode: 1=bytes, 0=words.
__global__ void detect_mode_kernel(const unsigned int* __restrict__ m,
                                   int* __restrict__ mode) {
    __shared__ int any_gt1, any_f32;
    if (threadIdx.x == 0) { any_gt1 = 0; any_f32 = 0; }
    __syncthreads();
    int lgt1 = 0, lf32 = 0;
    for (int i = threadIdx.x; i < L_DIM; i += blockDim.x) {
        unsigned int w = m[i];
        if (w == 0x3f800000u)      lf32 = 1;
        else if (w > 1u)           lgt1 = 1;
    }
    if (lgt1) any_gt1 = 1;   // benign same-value race
    if (lf32) any_f32 = 1;
    __syncthreads();
    if (threadIdx.x == 0)
        *mode = (any_f32 ? 0 : (any_gt1 ? 1 : 0));
}

// bit j = (byte j of w) != 0, packed into low nibble. Bools are 0/1 bytes but
// this is robust to any nonzero encoding. No cross-byte contamination: >>4
// leakage can only reach bit 1 (4 > 2+1), and we keep bit 0 per byte.
__device__ __forceinline__ unsigned int byte_nib(unsigned int w) {
    unsigned int nz = w | (w >> 4);
    nz |= nz >> 2;
    nz |= nz >> 1;
    nz &= 0x01010101u;
    return (nz * 0x01020408u) >> 24;   // b0 | b1<<1 | b2<<2 | b3<<3
}

// ---- main kernel ------------------------------------------------------------
// One wave per row. Lane l owns float4 chunks c = l + 64*m, m=0..15 (elements
// 4l+256m .. 4l+256m+3) -> every wave memory instr spans contiguous 1 KB.
// No LDS, no __syncthreads: reduction is wave-local shfl_xor butterfly.
__global__ __launch_bounds__(256, 8)
void subset_kernel(const float* __restrict__ x,
                   const void* __restrict__ mask,
                   const int* __restrict__ mode_p,
                   float* __restrict__ out_x,
                   float* __restrict__ out_mask,
                   int B) {
    const int lane = threadIdx.x & 63;
    const int row  = (blockIdx.x << 2) + (threadIdx.x >> 6);
    if (row >= B) return;

    const int mode = *mode_p;                 // wave-uniform scalar load
    const size_t rowoff = (size_t)row * L_DIM;

    const f32x4* xr  = (const f32x4*)(x        + rowoff);
    f32x4*       oxr = (f32x4*)      (out_x    + rowoff);
    f32x4*       omr = (f32x4*)      (out_mask + rowoff);

    // bit (4m+j) = mask value of element 4*lane + 256*m + j
    unsigned long long bits = 0ull;
    f32x4 xa[4], xb[4];                       // depth-2 x staging (32 VGPR)

    if (mode == 1) {
        // 1-byte bools: dword at word index c covers chunk c's 4 elements.
        const unsigned int* mp =
            (const unsigned int*)((const unsigned char*)mask + rowoff);
        unsigned int mw[16];
        #pragma unroll
        for (int m = 0; m < 16; ++m)          // all mask loads in flight first
            mw[m] = __builtin_nontemporal_load(&mp[lane + 64 * m]);
        #pragma unroll
        for (int j = 0; j < 4; ++j)           // x batch 0 (m = 0..3)
            xa[j] = __builtin_nontemporal_load(&xr[lane + 64 * j]);
        #pragma unroll
        for (int j = 0; j < 4; ++j)           // x batch 1 (m = 4..7)
            xb[j] = __builtin_nontemporal_load(&xr[lane + 64 * (4 + j)]);
        #pragma unroll
        for (int m = 0; m < 16; ++m)          // consume; waits mask vmcnt only
            bits |= (unsigned long long)byte_nib(mw[m]) << (4 * m);
    } else {
        // 4-byte elements (int32 0/1 or f32 bits): nonzero word == True.
        // Grouped 4-at-a-time to bound registers (word mode is the rare path).
        const u32x4* mp = (const u32x4*)((const unsigned int*)mask + rowoff);
        #pragma unroll
        for (int g = 0; g < 4; ++g) {
            u32x4 q[4];
            #pragma unroll
            for (int j = 0; j < 4; ++j)
                q[j] = __builtin_nontemporal_load(&mp[lane + 64 * (4 * g + j)]);
            #pragma unroll
            for (int j = 0; j < 4; ++j) {
                unsigned int nib = (q[j].x ? 1u : 0u) | (q[j].y ? 2u : 0u)
                                 | (q[j].z ? 4u : 0u) | (q[j].w ? 8u : 0u);
                bits |= (unsigned long long)nib << (4 * (4 * g + j));
            }
        }
        #pragma unroll
        for (int j = 0; j < 4; ++j)
            xa[j] = __builtin_nontemporal_load(&xr[lane + 64 * j]);
        #pragma unroll
        for (int j = 0; j < 4; ++j)
            xb[j] = __builtin_nontemporal_load(&xr[lane + 64 * (4 + j)]);
    }

    // ---- wave-local False count + butterfly (all lanes get the total) ----
    int zeros = 64 - __popcll(bits);
    #pragma unroll
    for (int off = 1; off < 64; off <<= 1)
        zeros += __shfl_xor(zeros, off, 64);

    // exact match to jnp: f32 multiply (one rounding), f32 ceil, min
    const int cutoff = min((int)ceilf((float)zeros * SUBSET_RATE), L_DIM - 1);

    // ---- x copy pipeline: store batch, refill same regs with batch+2 ----
    #pragma unroll
    for (int j = 0; j < 4; ++j)
        __builtin_nontemporal_store(xa[j], &oxr[lane + 64 * j]);
    #pragma unroll
    for (int j = 0; j < 4; ++j)               // batch 2 (m = 8..11)
        xa[j] = __builtin_nontemporal_load(&xr[lane + 64 * (8 + j)]);
    #pragma unroll
    for (int j = 0; j < 4; ++j)
        __builtin_nontemporal_store(xb[j], &oxr[lane + 64 * (4 + j)]);
    #pragma unroll
    for (int j = 0; j < 4; ++j)               // batch 3 (m = 12..15)
        xb[j] = __builtin_nontemporal_load(&xr[lane + 64 * (12 + j)]);

    // ---- mask stores, first half: pipe work while batches 2/3 in flight ----
    #pragma unroll
    for (int m = 0; m < 8; ++m) {
        const int i0 = 4 * lane + 256 * m;
        const unsigned int nib = (unsigned int)(bits >> (4 * m)) & 0xFu;
        f32x4 mv;
        mv.x = ((nib & 1u) || (i0 + 0 >= cutoff)) ? 1.0f : 0.0f;
        mv.y = ((nib & 2u) || (i0 + 1 >= cutoff)) ? 1.0f : 0.0f;
        mv.z = ((nib & 4u) || (i0 + 2 >= cutoff)) ? 1.0f : 0.0f;
        mv.w = ((nib & 8u) || (i0 + 3 >= cutoff)) ? 1.0f : 0.0f;
        __builtin_nontemporal_store(mv, &omr[lane + 64 * m]);
    }
    #pragma unroll
    for (int j = 0; j < 4; ++j)
        __builtin_nontemporal_store(xa[j], &oxr[lane + 64 * (8 + j)]);
    #pragma unroll
    for (int m = 8; m < 16; ++m) {
        const int i0 = 4 * lane + 256 * m;
        const unsigned int nib = (unsigned int)(bits >> (4 * m)) & 0xFu;
        f32x4 mv;
        mv.x = ((nib & 1u) || (i0 + 0 >= cutoff)) ? 1.0f : 0.0f;
        mv.y = ((nib & 2u) || (i0 + 1 >= cutoff)) ? 1.0f : 0.0f;
        mv.z = ((nib & 4u) || (i0 + 2 >= cutoff)) ? 1.0f : 0.0f;
        mv.w = ((nib & 8u) || (i0 + 3 >= cutoff)) ? 1.0f : 0.0f;
        __builtin_nontemporal_store(mv, &omr[lane + 64 * m]);
    }
    #pragma unroll
    for (int j = 0; j < 4; ++j)
        __builtin_nontemporal_store(xb[j], &oxr[lane + 64 * (12 + j)]);
}

extern "C" void kernel_launch(void* const* d_in, const int* in_sizes, int n_in,
                              void* d_out, int out_size, void* d_ws, size_t ws_size,
                              hipStream_t stream) {
    const float* x    = (const float*)d_in[0];
    const void*  mask = d_in[1];
    const int B = in_sizes[0] / L_DIM;            // 8192

    float* out_x    = (float*)d_out;              // first B*L floats
    float* out_mask = out_x + (size_t)B * L_DIM;  // next B*L floats (0.0/1.0)
    int*   mode     = (int*)d_ws;                 // rewritten every call

    detect_mode_kernel<<<1, 256, 0, stream>>>((const unsigned int*)mask, mode);
    subset_kernel<<<(B + 3) / 4, 256, 0, stream>>>(x, mask, mode, out_x, out_mask, B);
}

// Round 3
// 420.297 us; speedup vs baseline: 1.0410x; 1.0410x over previous
//
#include <hip/hip_runtime.h>

// SubsetSampler: out0 = x (f32 passthrough), out1 = float(mask | (l >= cutoff)),
// cutoff_b = min(ceil(0.7 * count_false(mask[b,:])), L-1).  B=8192, L=4096.
//
// R7 = revert to the proven R4 block-per-row structure. R5/R6 post-mortem:
// wave-per-row + software pipelining both REGRESSED (423 -> 428 -> 438):
// R5 blew VGPRs (4 waves/SIMD), R6's store->refill register reuse forced
// vmcnt serialization. R4 was already at the mixed-stream roofline:
// word-mode traffic = 512 MiB (x r/w 128+128, mask r/w 128+128) @ 6.29 TB/s
// measured copy ceiling = 85.4 us ~= observed remainder. Only change vs R4:
// single-barrier cutoff broadcast (each thread sums the 4 wave partials from
// LDS and computes cutoff locally) instead of two __syncthreads + t==0 serial.

#define L_DIM 4096
#define SUBSET_RATE 0.7f

typedef float        f32x4 __attribute__((ext_vector_type(4)));
typedef unsigned int u32x4 __attribute__((ext_vector_type(4)));

// ---- mask-storage detection (1 block, 16 KB read, ~5 us) --------------------
// byte bools: padding runs of 0x01 -> some word > 1 in the first 4096 words.
// f32 bools: word 0x3f800000. int32 bools: words 0/1 only. Word-sized layouts
// (int32/f32) share the decode path (nonzero == True). mode: 1=bytes, 0=words.
__global__ void detect_mode_kernel(const unsigned int* __restrict__ m,
                                   int* __restrict__ mode) {
    __shared__ int any_gt1, any_f32;
    if (threadIdx.x == 0) { any_gt1 = 0; any_f32 = 0; }
    __syncthreads();
    int lgt1 = 0, lf32 = 0;
    for (int i = threadIdx.x; i < L_DIM; i += blockDim.x) {
        unsigned int w = m[i];
        if (w == 0x3f800000u)      lf32 = 1;
        else if (w > 1u)           lgt1 = 1;
    }
    if (lgt1) any_gt1 = 1;   // benign same-value race
    if (lf32) any_f32 = 1;
    __syncthreads();
    if (threadIdx.x == 0)
        *mode = (any_f32 ? 0 : (any_gt1 ? 1 : 0));
}

// ---- main kernel ------------------------------------------------------------
// One block per row, 256 threads. Thread t owns float4 chunks c = t + 256*k,
// k=0..3 (elements 4c..4c+3) -> every wave memory instr spans contiguous 4 KB.
__global__ __launch_bounds__(256)
void subset_kernel(const float* __restrict__ x,
                   const void* __restrict__ mask,
                   const int* __restrict__ mode_p,
                   float* __restrict__ out_x,
                   float* __restrict__ out_mask) {
    const int row  = blockIdx.x;
    const int t    = threadIdx.x;
    const int mode = *mode_p;                 // wave-uniform scalar load
    const size_t rowoff = (size_t)row * L_DIM;

    const f32x4* xr  = (const f32x4*)(x        + rowoff);
    f32x4*       oxr = (f32x4*)      (out_x    + rowoff);
    f32x4*       omr = (f32x4*)      (out_mask + rowoff);

    unsigned int bits = 0;   // bit (4k+j) = mask value of element 4*(t+256k)+j

    if (mode == 1) {
        // 1-byte bools: uint32 at word index c covers the chunk's 4 elements.
        const unsigned int* mp =
            (const unsigned int*)((const unsigned char*)mask + rowoff);
        unsigned int mw[4];
        #pragma unroll
        for (int k = 0; k < 4; ++k)                       // mask loads first:
            mw[k] = __builtin_nontemporal_load(&mp[t + 256 * k]);
        f32x4 xv[4];
        #pragma unroll
        for (int k = 0; k < 4; ++k)                       // x loads overlap
            xv[k] = __builtin_nontemporal_load(&xr[t + 256 * k]);
        #pragma unroll
        for (int k = 0; k < 4; ++k) {
            #pragma unroll
            for (int j = 0; j < 4; ++j)
                if ((mw[k] >> (8 * j)) & 0xffu) bits |= 1u << (4 * k + j);
        }
        #pragma unroll
        for (int k = 0; k < 4; ++k)
            __builtin_nontemporal_store(xv[k], &oxr[t + 256 * k]);
    } else {
        // 4-byte elements (int32 0/1 or f32 bits): nonzero word == True.
        const u32x4* mp = (const u32x4*)((const unsigned int*)mask + rowoff);
        u32x4 mw[4];
        #pragma unroll
        for (int k = 0; k < 4; ++k)
            mw[k] = __builtin_nontemporal_load(&mp[t + 256 * k]);
        f32x4 xv[4];
        #pragma unroll
        for (int k = 0; k < 4; ++k)
            xv[k] = __builtin_nontemporal_load(&xr[t + 256 * k]);
        #pragma unroll
        for (int k = 0; k < 4; ++k) {
            if (mw[k].x) bits |= 1u << (4 * k + 0);
            if (mw[k].y) bits |= 1u << (4 * k + 1);
            if (mw[k].z) bits |= 1u << (4 * k + 2);
            if (mw[k].w) bits |= 1u << (4 * k + 3);
        }
        #pragma unroll
        for (int k = 0; k < 4; ++k)
            __builtin_nontemporal_store(xv[k], &oxr[t + 256 * k]);
    }

    int zeros = 16 - __popc(bits);            // False count this thread saw

    // ---- block reduction: wave shuffle -> LDS partials -> ONE barrier,
    // then every thread sums the 4 partials (LDS broadcast) locally.
    #pragma unroll
    for (int off = 32; off > 0; off >>= 1)
        zeros += __shfl_down(zeros, off, 64);
    __shared__ int partial[4];
    if ((t & 63) == 0) partial[t >> 6] = zeros;
    __syncthreads();
    const int len = partial[0] + partial[1] + partial[2] + partial[3];
    // exact match to jnp: f32 multiply (one rounding), f32 ceil, min
    const int cutoff = min((int)ceilf((float)len * SUBSET_RATE), L_DIM - 1);

    // ---- coalesced nontemporal mask writes ----
    #pragma unroll
    for (int k = 0; k < 4; ++k) {
        const int c  = t + 256 * k;
        const int i0 = c * 4;
        f32x4 mv;
        mv.x = (((bits >> (4 * k + 0)) & 1u) || (i0 + 0 >= cutoff)) ? 1.0f : 0.0f;
        mv.y = (((bits >> (4 * k + 1)) & 1u) || (i0 + 1 >= cutoff)) ? 1.0f : 0.0f;
        mv.z = (((bits >> (4 * k + 2)) & 1u) || (i0 + 2 >= cutoff)) ? 1.0f : 0.0f;
        mv.w = (((bits >> (4 * k + 3)) & 1u) || (i0 + 3 >= cutoff)) ? 1.0f : 0.0f;
        __builtin_nontemporal_store(mv, &omr[c]);
    }
}

extern "C" void kernel_launch(void* const* d_in, const int* in_sizes, int n_in,
                              void* d_out, int out_size, void* d_ws, size_t ws_size,
                              hipStream_t stream) {
    const float* x    = (const float*)d_in[0];
    const void*  mask = d_in[1];
    const int B = in_sizes[0] / L_DIM;            // 8192

    float* out_x    = (float*)d_out;              // first B*L floats
    float* out_mask = out_x + (size_t)B * L_DIM;  // next B*L floats (0.0/1.0)
    int*   mode     = (int*)d_ws;                 // rewritten every call

    detect_mode_kernel<<<1, 256, 0, stream>>>((const unsigned int*)mask, mode);
    subset_kernel<<<B, 256, 0, stream>>>(x, mask, mode, out_x, out_mask);
}